// Round 7
// baseline (29.736 us; speedup 1.0000x reference)
//
#include <hip/hip_runtime.h>

#define NB    32
#define NT    8192
#define NF    128
#define NOUT  1024
#define NSEG  256          // 32-row segments per batch
#define NGRP  64           // 128-row groups per batch
#define TILE  32           // outputs per phase-2 tile
#define NTILE (NOUT/TILE)  // 32 tiles per batch

__device__ __forceinline__ float4 f4add(float4 a, float4 b) {
  return make_float4(a.x + b.x, a.y + b.y, a.z + b.z, a.w + b.w);
}
__device__ __forceinline__ float4 f4sub(float4 a, float4 b) {
  return make_float4(a.x - b.x, a.y - b.y, a.z - b.z, a.w - b.w);
}

// ---- R5-proven phase-1 body: one 128-row group -> 4x S32 + 1x S128 ----
__device__ __forceinline__ void phase1_group(const float4* __restrict__ xb,
                                             int b, int g, int len,
                                             float* __restrict__ S32,
                                             float* __restrict__ S128,
                                             int tl, int fl, float4 (*red)[32]) {
  if (g * 128 < len) {                           // block-uniform
    const float4* xp = xb + (size_t)(g * 128) * 32;
    float4 acc = make_float4(0.f, 0.f, 0.f, 0.f);
    #pragma unroll
    for (int r = 0; r < 16; ++r)
      acc = f4add(acc, xp[(tl * 16 + r) * 32]);
    red[tl][fl] = acc;
    __syncthreads();
    if (tl < 4) {
      float4 s = f4add(red[2 * tl][fl], red[2 * tl + 1][fl]);
      reinterpret_cast<float4*>(S32 + ((size_t)b * NSEG + g * 4 + tl) * NF)[fl] = s;
    } else if (tl == 4) {
      float4 s = f4add(f4add(red[0][fl], red[1][fl]),
                       f4add(red[2][fl], red[3][fl]));
      s = f4add(s, f4add(f4add(red[4][fl], red[5][fl]),
                         f4add(red[6][fl], red[7][fl])));
      reinterpret_cast<float4*>(S128 + ((size_t)b * NGRP + g) * NF)[fl] = s;
    }
    __syncthreads();                             // red reused later
  }
}

// ---- R5-proven phase-2 body: one 32-output tile, hierarchical assembly ----
__device__ __forceinline__ void phase2_tile(const float4* __restrict__ xb,
                                            int b, int tile, int len,
                                            const float* __restrict__ S32,
                                            const float* __restrict__ S128,
                                            float* __restrict__ out,
                                            int tl, int fl, float4 (*red)[32]) {
  const int W    = len - NOUT + 1;               // [2, 7169]
  const int t0   = tile * TILE;
  const int p1   = t0 + W;                       // <= 8161
  const int s_hi = p1 >> 5;
  const int g_lo = (t0 + 127) >> 7;
  const int g_hi = p1 >> 7;

  const float4* S32b  = reinterpret_cast<const float4*>(S32  + (size_t)b * NSEG * NF) + fl;
  const float4* S128b = reinterpret_cast<const float4*>(S128 + (size_t)b * NGRP * NF) + fl;

  float4 acc = make_float4(0.f, 0.f, 0.f, 0.f);
  if (g_hi > g_lo) {
    for (int s = tile + tl; s < 4 * g_lo; s += 8)
      acc = f4add(acc, S32b[s * 32]);
    for (int g = g_lo + tl; g < g_hi; g += 8)
      acc = f4add(acc, S128b[g * 32]);
    for (int s = 4 * g_hi + tl; s < s_hi; s += 8)
      acc = f4add(acc, S32b[s * 32]);
  } else {
    for (int s = tile + tl; s < s_hi; s += 8)
      acc = f4add(acc, S32b[s * 32]);
  }
  for (int j = (s_hi << 5) + tl; j < p1; j += 8) // remainder rows (<32)
    acc = f4add(acc, xb[j * 32]);

  red[tl][fl] = acc;
  __syncthreads();
  float4 A = make_float4(0.f, 0.f, 0.f, 0.f);
  #pragma unroll
  for (int k = 0; k < 8; ++k) A = f4add(A, red[k][fl]);
  __syncthreads();

  float4 D = make_float4(0.f, 0.f, 0.f, 0.f);
  if (tl < 7) {                                  // lane 7 unused (OOB guard)
    const int baseLo = t0 + 4 * tl;
    const int baseHi = p1 + 4 * tl;
    #pragma unroll
    for (int j = 0; j < 4; ++j)
      D = f4add(D, f4sub(xb[(baseHi + j) * 32], xb[(baseLo + j) * 32]));
  }
  red[tl][fl] = D;
  __syncthreads();
  #pragma unroll
  for (int k = 0; k < 7; ++k)
    if (k < tl) A = f4add(A, red[k][fl]);        // exclusive prefix

  const float invW  = 1.0f / (float)W;
  const int   tbase = t0 + 4 * tl;
  float4* ob = reinterpret_cast<float4*>(out + ((size_t)b * NOUT + tbase) * NF) + fl;

  #pragma unroll
  for (int i = 0; i < 4; ++i) {
    ob[i * 32] = make_float4(A.x * invW, A.y * invW, A.z * invW, A.w * invW);
    if (i < 3) {                                 // last update dead; max idx 8191
      float4 h = xb[(tbase + i + W) * 32];
      float4 l = xb[(tbase + i) * 32];
      A = f4add(A, f4sub(h, l));
    }
  }
}

// ---- Fused pipelined kernel: 2048 blocks, all co-resident (8/CU at <=64 VGPR).
// Block (b,g): phase-1 group g of batch b; release-increment done[b];
// blocks with g < NTILE then acquire-spin for done[b]==64 and run tile g.
__global__ __launch_bounds__(256) void fused_pipe(const float* __restrict__ x,
                                                  const int* __restrict__ lengths,
                                                  float* __restrict__ S32,
                                                  float* __restrict__ S128,
                                                  unsigned int* __restrict__ done,
                                                  float* __restrict__ out) {
  const int bid = blockIdx.x;
  const int wg  = ((bid & 7) << 8) | (bid >> 3);   // bijective XCD swizzle
  const int b   = wg >> 6;
  const int g   = wg & 63;
  const int len = lengths[b];
  const int tid = threadIdx.x;
  const int fl  = tid & 31;
  const int tl  = tid >> 5;

  __shared__ float4 red[8][32];
  const float4* xb = reinterpret_cast<const float4*>(x + (size_t)b * NT * NF) + fl;

  phase1_group(xb, b, g, len, S32, S128, tl, fl, red);

  __threadfence();                 // device-scope release of this block's S writes
  __syncthreads();                 // all threads' fences precede the increment
  if (tid == 0)
    __hip_atomic_fetch_add(&done[b], 1u, __ATOMIC_RELEASE, __HIP_MEMORY_SCOPE_AGENT);

  if (g < NTILE) {
    if (tid == 0) {
      while (__hip_atomic_load(&done[b], __ATOMIC_ACQUIRE, __HIP_MEMORY_SCOPE_AGENT)
             < (unsigned)NGRP)
        __builtin_amdgcn_s_sleep(8);
    }
    __syncthreads();               // broadcast acquired view to the block
    phase2_tile(xb, b, g, len, S32, S128, out, tl, fl, red);
  }
}

// ---- R5-proven fallback (used only if VGPR > 64 breaks residency) ----
__global__ __launch_bounds__(256) void k_seg(const float* __restrict__ x,
                                             const int* __restrict__ lengths,
                                             float* __restrict__ S32,
                                             float* __restrict__ S128) {
  const int blk = blockIdx.x;
  const int b   = blk >> 6;
  const int g   = blk & 63;
  const int len = lengths[b];
  const int tid = threadIdx.x;
  __shared__ float4 red[8][32];
  const float4* xb = reinterpret_cast<const float4*>(x + (size_t)b * NT * NF) + (tid & 31);
  phase1_group(xb, b, g, len, S32, S128, tid >> 5, tid & 31, red);
}

__global__ __launch_bounds__(256) void k_win(const float* __restrict__ x,
                                             const int* __restrict__ lengths,
                                             const float* __restrict__ S32,
                                             const float* __restrict__ S128,
                                             float* __restrict__ out) {
  const int wg   = ((blockIdx.x & 7) << 7) + (blockIdx.x >> 3);
  const int b    = wg >> 5;
  const int tile = wg & (NTILE - 1);
  const int len  = lengths[b];
  const int tid  = threadIdx.x;
  __shared__ float4 red[8][32];
  const float4* xb = reinterpret_cast<const float4*>(x + (size_t)b * NT * NF) + (tid & 31);
  phase2_tile(xb, b, tile, len, S32, S128, out, tid >> 5, tid & 31, red);
}

extern "C" void kernel_launch(void* const* d_in, const int* in_sizes, int n_in,
                              void* d_out, int out_size, void* d_ws, size_t ws_size,
                              hipStream_t stream) {
  const float* x       = (const float*)d_in[0];
  const int*   lengths = (const int*)d_in[1];
  float*       S32     = (float*)d_ws;                            // 4 MB
  float*       S128    = (float*)d_ws + (size_t)NB * NSEG * NF;   // +1 MB
  unsigned int* done   = (unsigned int*)((float*)d_ws +
                          (size_t)NB * (NSEG + NGRP) * NF);       // +128 B
  float*       out     = (float*)d_out;

  hipFuncAttributes attr{};
  bool pipe_ok = (hipFuncGetAttributes(&attr, (const void*)fused_pipe) == hipSuccess)
                 && attr.numRegs <= 64;   // 8 blocks/CU residency guarantee

  if (pipe_ok) {
    hipMemsetAsync(done, 0, NB * sizeof(unsigned int), stream);
    hipLaunchKernelGGL(fused_pipe, dim3(NB * NGRP), dim3(256), 0, stream,
                       x, lengths, S32, S128, done, out);
  } else {
    hipLaunchKernelGGL(k_seg, dim3(NB * NGRP), dim3(256), 0, stream,
                       x, lengths, S32, S128);
    hipLaunchKernelGGL(k_win, dim3(NB * NTILE), dim3(256), 0, stream,
                       x, lengths, S32, S128, out);
  }
}